// Round 9
// baseline (263.483 us; speedup 1.0000x reference)
//
#include <hip/hip_runtime.h>

#define SUB_NO 20
#define E_NO   2000
#define I_NO   500
#define T_NO   201
#define BATCH  4
#define T_DATA 20000

#define WARM   (T_NO - 1)      // 200
#define CCHUNK 120
#define XROW   (WARM + CCHUNK) // 320
#define XPAD   (XROW + 1)

#define NKS_E  64              // E kpad 2048 / 32
#define NKS_I  16              // I kpad 512 / 32
#define EBUF_B 65536           // [16 t][4096 B] bf16 rows
#define IBUF_B 16384           // [16 t][1024 B]

typedef unsigned short ush;
typedef short  bf16x8 __attribute__((ext_vector_type(8)));
typedef float  f32x4  __attribute__((ext_vector_type(4)));
typedef float  f4     __attribute__((ext_vector_type(4)));

__device__ __forceinline__ f4 ntload(const float* p) {     // streaming read: no L2/L3 alloc
    return __builtin_nontemporal_load((const f4*)p);
}

__device__ __forceinline__ bf16x8 pack8(f4 x, f4 y) {      // RTNE via HW cvt_pk
    union { unsigned u[4]; bf16x8 v; } r;
    asm("v_cvt_pk_bf16_f32 %0, %1, %2" : "=v"(r.u[0]) : "v"(x[0]), "v"(x[1]));
    asm("v_cvt_pk_bf16_f32 %0, %1, %2" : "=v"(r.u[1]) : "v"(x[2]), "v"(x[3]));
    asm("v_cvt_pk_bf16_f32 %0, %1, %2" : "=v"(r.u[2]) : "v"(y[0]), "v"(y[1]));
    asm("v_cvt_pk_bf16_f32 %0, %1, %2" : "=v"(r.u[3]) : "v"(y[2]), "v"(y[3]));
    return r.v;
}

// ---------------- K0: build bf16 one-hot A-operand fragments from C ----------------
// A layout (16x16x32): lane holds A[row=lane&15][k=(lane>>4)*8+j].
__global__ void k_build_afrag(const float* __restrict__ Ce, const float* __restrict__ Ci,
                              ush* __restrict__ Ae, ush* __restrict__ Ai) {
    int g = blockIdx.x * 256 + threadIdx.x;
    int isE = g < 2 * NKS_E * 64;
    int rem = isE ? g : g - 2 * NKS_E * 64;
    if (!isE && rem >= 2 * NKS_I * 64) return;
    int nks = isE ? NKS_E : NKS_I;
    int KD  = isE ? E_NO : I_NO;
    const float* C = isE ? Ce : Ci;
    int lane = rem & 63, kstep = (rem >> 6) % nks, rt = (rem >> 6) / nks;
    int row = rt * 16 + (lane & 15), hi = lane >> 4;
    ush* dst = (isE ? Ae : Ai) + (size_t)rem * 8;
    #pragma unroll
    for (int j = 0; j < 8; ++j) {
        int k = kstep * 32 + hi * 8 + j;
        dst[j] = (row < SUB_NO && k < KD && C[row * KD + k] != 0.0f) ? (ush)0x3F80 : (ush)0;
    }
}

// ---------------- K1: row-sequential staging GEMM + NON-TEMPORAL stream reads ------
__global__ __launch_bounds__(256) void k_proj(
        const float* __restrict__ S_e, const float* __restrict__ S_i,
        const ush* __restrict__ Ae, const ush* __restrict__ Ai,
        float* __restrict__ syn_e, float* __restrict__ syn_i) {
    __shared__ __align__(16) char lds[EBUF_B + IBUF_B];   // 80 KB -> 2 blocks/CU
    const int tid = threadIdx.x, w = tid >> 6, lane = tid & 63;
    const int col = lane & 15, hi = lane >> 4;
    const int b = blockIdx.y, t0 = blockIdx.x * 16;
    const size_t bT = (size_t)b * T_DATA;

    // ---- E fetch: wave w stages rows 4w..4w+3, each row = 8 x 1KB contiguous ----
    {
        const float* r0 = S_e + (bT + t0 + 4 * w) * (size_t)E_NO;
        f4 sA[8], sB[8];
        auto LR = [&](f4* s, int r4) {
            const float* rp = r0 + (size_t)r4 * E_NO;
            #pragma unroll
            for (int i = 0; i < 4; ++i) {
                int off = lane * 8 + i * 512;
                off = off > E_NO - 8 ? E_NO - 8 : off;   // tail dup; A=0 on pad-K
                s[2 * i]     = ntload(rp + off);
                s[2 * i + 1] = ntload(rp + off + 4);
            }
        };
        auto CW = [&](const f4* s, int r4) {
            int r = 4 * w + r4;
            char* dst = lds + r * 4096 + ((lane ^ (r & 7)) << 4);   // granule XOR swizzle
            #pragma unroll
            for (int i = 0; i < 4; ++i)
                *(bf16x8*)(dst + i * 1024) = pack8(s[2 * i], s[2 * i + 1]);
        };
        LR(sA, 0); LR(sB, 1); CW(sA, 0); LR(sA, 2); CW(sB, 1);
        LR(sB, 3); CW(sA, 2); CW(sB, 3);
    }
    // ---- I fetch: wave w rows 4w..4w+3, 2KB each ----
    {
        const float* r0 = S_i + (bT + t0 + 4 * w) * (size_t)I_NO;
        f4 sA[8];
        int off = lane * 8; off = off > I_NO - 8 ? I_NO - 8 : off;
        #pragma unroll
        for (int r4 = 0; r4 < 4; ++r4) {
            const float* rp = r0 + (size_t)r4 * I_NO;
            sA[2 * r4]     = ntload(rp + off);
            sA[2 * r4 + 1] = ntload(rp + off + 4);
        }
        #pragma unroll
        for (int r4 = 0; r4 < 4; ++r4) {
            int r = 4 * w + r4;
            *(bf16x8*)(lds + EBUF_B + r * 1024 + ((lane ^ (r & 7)) << 4)) =
                pack8(sA[2 * r4], sA[2 * r4 + 1]);
        }
    }
    __syncthreads();

    // ---- E compute: K-split, wave w ksteps [16w, 16w+16); A pipelined from L2 ----
    f32x4 acc_e[2], acc_i[2];
    { f32x4 z = {0.f, 0.f, 0.f, 0.f}; acc_e[0] = z; acc_e[1] = z; acc_i[0] = z; acc_i[1] = z; }
    const bf16x8* AeL = (const bf16x8*)Ae + lane;
    const bf16x8* AiL = (const bf16x8*)Ai + lane;

    auto LA_E = [&](bf16x8* a, int ksb) {          // 8 frags = group of 4 ksteps x 2 rt
        #pragma unroll
        for (int k = 0; k < 4; ++k) {
            a[2 * k]     = AeL[(size_t)(0 * NKS_E + ksb + k) * 64];
            a[2 * k + 1] = AeL[(size_t)(1 * NKS_E + ksb + k) * 64];
        }
    };
    auto CG_E = [&](const bf16x8* a, int ksb) {
        #pragma unroll
        for (int k = 0; k < 4; ++k) {
            int g = (ksb + k) * 4 + hi;
            bf16x8 bb = *(const bf16x8*)(lds + col * 4096 + ((g ^ (col & 7)) << 4));
            acc_e[0] = __builtin_amdgcn_mfma_f32_16x16x32_bf16(a[2 * k],     bb, acc_e[0], 0, 0, 0);
            acc_e[1] = __builtin_amdgcn_mfma_f32_16x16x32_bf16(a[2 * k + 1], bb, acc_e[1], 0, 0, 0);
        }
    };
    {
        bf16x8 a0[8], a1[8];
        const int ks0 = w * 16;
        LA_E(a0, ks0);
        LA_E(a1, ks0 + 4);  CG_E(a0, ks0);
        LA_E(a0, ks0 + 8);  CG_E(a1, ks0 + 4);
        LA_E(a1, ks0 + 12); CG_E(a0, ks0 + 8);
        CG_E(a1, ks0 + 12);
    }
    // ---- I compute: wave w ksteps [4w, 4w+4) ----
    {
        bf16x8 ai[8];
        const int ksI = w * 4;
        #pragma unroll
        for (int k = 0; k < 4; ++k) {
            ai[2 * k]     = AiL[(size_t)(0 * NKS_I + ksI + k) * 64];
            ai[2 * k + 1] = AiL[(size_t)(1 * NKS_I + ksI + k) * 64];
        }
        #pragma unroll
        for (int k = 0; k < 4; ++k) {
            int g = (ksI + k) * 4 + hi;
            bf16x8 bb = *(const bf16x8*)(lds + EBUF_B + col * 1024 + ((g ^ (col & 7)) << 4));
            acc_i[0] = __builtin_amdgcn_mfma_f32_16x16x32_bf16(ai[2 * k],     bb, acc_i[0], 0, 0, 0);
            acc_i[1] = __builtin_amdgcn_mfma_f32_16x16x32_bf16(ai[2 * k + 1], bb, acc_i[1], 0, 0, 0);
        }
    }
    __syncthreads();   // all waves done reading buffers

    // ---- cross-wave K-reduce (reuse buffer LDS) ----
    float* red = (float*)lds;
    float* myE = red + (size_t)(w * 64 + lane) * 8;
    float* myI = red + 2048 + (size_t)(w * 64 + lane) * 8;
    *(f32x4*)(myE)     = acc_e[0];
    *(f32x4*)(myE + 4) = acc_e[1];
    *(f32x4*)(myI)     = acc_i[0];
    *(f32x4*)(myI + 4) = acc_i[1];
    __syncthreads();
    if (w < 2) {
        const float* base = red + (w ? 2048 : 0);
        float* dst = w ? syn_i : syn_e;
        float v[8];
        #pragma unroll
        for (int i = 0; i < 2; ++i) {
            float4 s0 = *(const float4*)(base + (size_t)(0 * 64 + lane) * 8 + i * 4);
            float4 s1 = *(const float4*)(base + (size_t)(1 * 64 + lane) * 8 + i * 4);
            float4 s2 = *(const float4*)(base + (size_t)(2 * 64 + lane) * 8 + i * 4);
            float4 s3 = *(const float4*)(base + (size_t)(3 * 64 + lane) * 8 + i * 4);
            v[i * 4 + 0] = s0.x + s1.x + s2.x + s3.x;
            v[i * 4 + 1] = s0.y + s1.y + s2.y + s3.y;
            v[i * 4 + 2] = s0.z + s1.z + s2.z + s3.z;
            v[i * 4 + 3] = s0.w + s1.w + s2.w + s3.w;
        }
        #pragma unroll
        for (int rt = 0; rt < 2; ++rt)
            #pragma unroll
            for (int r = 0; r < 4; ++r) {
                int s = rt * 16 + (lane >> 4) * 4 + r;   // C/D: col=lane&15, row=(lane>>4)*4+reg
                if (s < SUB_NO)
                    dst[((size_t)b * SUB_NO + s) * T_DATA + t0 + (lane & 15)] = v[rt * 4 + r];
            }
    }
}

// ---------------- K2: fused IIR conv (exact alpha-kernel recurrence) + tree --------
__global__ __launch_bounds__(256) void k_convtree(
    const float* __restrict__ syn_e, const float* __restrict__ syn_i,
    const float* __restrict__ W_syn, const float* __restrict__ Tau_syn,
    const float* __restrict__ Delta_syn, const float* __restrict__ W_sub,
    const float* __restrict__ V_o, const float* __restrict__ Theta,
    const float* __restrict__ C_den, float* __restrict__ out) {
    __shared__ float x_lds[2 * SUB_NO][XPAD];
    __shared__ float y2[2 * SUB_NO][CCHUNK + 1];
    __shared__ float cden[SUB_NO * SUB_NO];
    __shared__ float wexp[SUB_NO];
    __shared__ float th[SUB_NO];

    const int tid = threadIdx.x;
    const int b   = blockIdx.y;
    const int t0  = blockIdx.x * CCHUNK;

    for (int r = 0; r < 2 * SUB_NO; ++r) {
        int s = r >> 1, ch = r & 1;
        const float* src = (ch ? syn_i : syn_e) + (size_t)(b * SUB_NO + s) * T_DATA;
        for (int i = tid; i < XROW; i += 256) {
            int t = t0 - WARM + i;
            x_lds[r][i] = (t >= 0 && t < T_DATA) ? src[t] : 0.0f;
        }
    }
    for (int i = tid; i < SUB_NO * SUB_NO; i += 256) cden[i] = C_den[i];
    if (tid < SUB_NO) { wexp[tid] = expf(W_sub[tid]); th[tid] = Theta[tid]; }
    __syncthreads();

    if (tid < 2 * SUB_NO) {
        int s = tid >> 1, ch = tid & 1;
        float Tp = expf(Tau_syn[s * 2 + ch]);
        float dp = expf(Delta_syn[s * 2 + ch]);
        float rr = expf(-1.0f / Tp);
        float Bc = expf(W_syn[s * 2 + ch]) * expf(dp / Tp) / Tp;
        float s1 = 0.0f, s2 = 0.0f;
        for (int i = 0; i < WARM; ++i) {
            float u = s1 + x_lds[tid][i];
            s2 = rr * (s2 + u);
            s1 = rr * u;
        }
        for (int i = WARM; i < XROW; ++i) {
            y2[tid][i - WARM] = Bc * (s2 - dp * s1);   // k[0]=0: state uses x[<t] only
            float u = s1 + x_lds[tid][i];
            s2 = rr * (s2 + u);
            s1 = rr * u;
        }
    }
    __syncthreads();

    if (tid < CCHUNK) {
        int tt = t0 + tid;
        if (tt < T_DATA) {
            float xs[SUB_NO];
            #pragma unroll
            for (int s = SUB_NO - 1; s >= 0; --s) {
                float leaf = 0.0f;
                #pragma unroll
                for (int k = s + 1; k < SUB_NO; ++k)
                    leaf += cden[s * SUB_NO + k] * wexp[k] * xs[k];
                xs[s] = tanhf(y2[2 * s][tid] + y2[2 * s + 1][tid] + leaf + th[s]);
            }
            out[(size_t)b * T_DATA + tt] = xs[0] * wexp[0] + V_o[0];
        }
    }
}

extern "C" void kernel_launch(void* const* d_in, const int* in_sizes, int n_in,
                              void* d_out, int out_size, void* d_ws, size_t ws_size,
                              hipStream_t stream) {
    const float* S_e       = (const float*)d_in[0];
    const float* S_i       = (const float*)d_in[1];
    const float* C_den     = (const float*)d_in[2];
    const float* C_syn_e   = (const float*)d_in[3];
    const float* C_syn_i   = (const float*)d_in[4];
    const float* W_syn     = (const float*)d_in[5];
    const float* Tau_syn   = (const float*)d_in[6];
    const float* Delta_syn = (const float*)d_in[7];
    const float* W_sub     = (const float*)d_in[8];
    const float* V_o       = (const float*)d_in[9];
    const float* Theta     = (const float*)d_in[10];
    float* out = (float*)d_out;

    size_t syn_elems = (size_t)BATCH * SUB_NO * T_DATA;
    float* syn_e_ws = (float*)d_ws;
    float* syn_i_ws = syn_e_ws + syn_elems;
    ush*   Ae       = (ush*)(syn_i_ws + syn_elems);          // 128 KiB
    ush*   Ai       = Ae + (size_t)2 * NKS_E * 64 * 8;       // 32 KiB

    hipLaunchKernelGGL(k_build_afrag, dim3((2 * NKS_E * 64 + 2 * NKS_I * 64 + 255) / 256),
                       dim3(256), 0, stream, C_syn_e, C_syn_i, Ae, Ai);
    hipLaunchKernelGGL(k_proj, dim3(T_DATA / 16, BATCH), dim3(256), 0, stream,
                       S_e, S_i, Ae, Ai, syn_e_ws, syn_i_ws);
    hipLaunchKernelGGL(k_convtree, dim3((T_DATA + CCHUNK - 1) / CCHUNK, BATCH), dim3(256), 0, stream,
                       syn_e_ws, syn_i_ws, W_syn, Tau_syn, Delta_syn, W_sub, V_o, Theta, C_den, out);
}

// Round 10
// 231.859 us; speedup vs baseline: 1.1364x; 1.1364x over previous
//
#include <hip/hip_runtime.h>

#define SUB_NO 20
#define E_NO   2000
#define I_NO   500
#define T_NO   201
#define BATCH  4
#define T_DATA 20000

#define WARM   (T_NO - 1)      // 200
#define CCHUNK 120
#define XROW   (WARM + CCHUNK) // 320
#define XPAD   (XROW + 1)

#define NKS_E  64              // E kpad 2048 / 32
#define NKS_I  16              // I kpad 512 / 32
#define NC_E16 16              // 128-e chunks, E
#define NC_TOT 20              // + 4 chunks I (512 pad)
#define CHUNKB 24576           // per-buffer LDS: 16KB B (32 rows x 512B) + 8KB A

typedef unsigned short ush;
typedef short  bf16x8 __attribute__((ext_vector_type(8)));
typedef float  f32x4  __attribute__((ext_vector_type(4)));

__device__ __forceinline__ bf16x8 pack8(float4 x, float4 y) {   // RTNE via HW cvt_pk
    union { unsigned u[4]; bf16x8 v; } r;
    asm("v_cvt_pk_bf16_f32 %0, %1, %2" : "=v"(r.u[0]) : "v"(x.x), "v"(x.y));
    asm("v_cvt_pk_bf16_f32 %0, %1, %2" : "=v"(r.u[1]) : "v"(x.z), "v"(x.w));
    asm("v_cvt_pk_bf16_f32 %0, %1, %2" : "=v"(r.u[2]) : "v"(y.x), "v"(y.y));
    asm("v_cvt_pk_bf16_f32 %0, %1, %2" : "=v"(r.u[3]) : "v"(y.z), "v"(y.w));
    return r.v;
}
__device__ __forceinline__ void gll16(const void* g, void* l) {
    __builtin_amdgcn_global_load_lds((const __attribute__((address_space(1))) unsigned*)g,
                                     (__attribute__((address_space(3))) unsigned*)l, 16, 0, 0);
}

// ---------------- K0: build bf16 one-hot A-operand fragments from C ----------------
// A layout (16x16x32): lane holds A[row=lane&15][k=(lane>>4)*8+j].
__global__ void k_build_afrag(const float* __restrict__ Ce, const float* __restrict__ Ci,
                              ush* __restrict__ Ae, ush* __restrict__ Ai) {
    int g = blockIdx.x * 256 + threadIdx.x;
    int isE = g < 2 * NKS_E * 64;
    int rem = isE ? g : g - 2 * NKS_E * 64;
    if (!isE && rem >= 2 * NKS_I * 64) return;
    int nks = isE ? NKS_E : NKS_I;
    int KD  = isE ? E_NO : I_NO;
    const float* C = isE ? Ce : Ci;
    int lane = rem & 63, kstep = (rem >> 6) % nks, rt = (rem >> 6) / nks;
    int row = rt * 16 + (lane & 15), hi = lane >> 4;
    ush* dst = (isE ? Ae : Ai) + (size_t)rem * 8;
    #pragma unroll
    for (int j = 0; j < 8; ++j) {
        int k = kstep * 32 + hi * 8 + j;
        dst[j] = (row < SUB_NO && k < KD && C[row * KD + k] != 0.0f) ? (ush)0x3F80 : (ush)0;
    }
}

// ---------------- K1: block-coop GEMM; sigma-swizzled A, cvt_pk pack ----------------
__global__ __launch_bounds__(256) void k_proj(
        const float* __restrict__ S_e, const float* __restrict__ S_i,
        const ush* __restrict__ Ae, const ush* __restrict__ Ai,
        float* __restrict__ syn_e, float* __restrict__ syn_i) {
    __shared__ __align__(16) char lds[2 * CHUNKB];
    const int tid = threadIdx.x, w = tid >> 6, lane = tid & 63;
    const int col = lane & 15, kq = (lane >> 4) * 2;
    const int b = blockIdx.y, t0 = blockIdx.x * 32;
    const size_t bT = (size_t)b * T_DATA;

    // sigma involution for A granules: conflict-free under consecutive AND
    // interleaved quarter-wave phase grouping of ds_read_b128.
    const int sl   = lane ^ ((lane >> 3) & 7);
    const int offA = 16384 + w * 2048 + (sl << 4);
    // B-read offsets: m = t&7 is identical for ct=0/1; f1 addr = f0 addr ^ 16.
    const int gB    = ((w * 8 + kq) ^ (col & 7)) << 4;
    const int offB0 = col * 512 + gB;
    const int offB1 = offB0 + 16 * 512;

    const float* sbE = S_e + (bT + t0) * (size_t)E_NO;
    const float* sbI = S_i + (bT + t0) * (size_t)I_NO;
    const int ls = lane >> 5, q = lane & 31;

    auto FILL = [&](int x) {                       // 6 gll16 per wave, uniform x
        if (x >= NC_TOT) return;
        char* buf = lds + (x & 1) * CHUNKB;
        const int isE = x < NC_E16;
        const float* sb = isE ? sbE : sbI;
        const int KD  = isE ? E_NO : I_NO;
        const int xc  = isE ? x : x - NC_E16;
        const int seg = xc * 128;
        #pragma unroll
        for (int i = 0; i < 4; ++i) {              // B: source-side XOR-swizzled granules
            int row = w * 8 + i * 2 + ls;
            int af  = seg + ((q ^ ((i * 2 + ls) & 7)) << 2);
            af = af > KD - 4 ? KD - 4 : af;        // pad-K dup; A=0 kills it
            gll16(sb + (size_t)row * KD + af, buf + (w * 8 + i * 2) * 512);
        }
        const ush* Af = isE ? Ae : Ai;             // A: sigma-swizzled source granule
        const int nks = isE ? NKS_E : NKS_I;
        const int ks  = xc * 4 + w;
        #pragma unroll
        for (int rt = 0; rt < 2; ++rt)
            gll16(Af + ((size_t)(rt * nks + ks) << 9) + sl * 8,
                  buf + 16384 + (w * 2 + rt) * 1024);
    };

    auto COMPUTE = [&](const char* buf, f32x4 (&acc)[2][2]) {
        bf16x8 a0 = *(const bf16x8*)(buf + offA);
        bf16x8 a1 = *(const bf16x8*)(buf + offA + 1024);
        #pragma unroll
        for (int ct = 0; ct < 2; ++ct) {
            int o = ct ? offB1 : offB0;
            float4 f0 = *(const float4*)(buf + o);
            float4 f1 = *(const float4*)(buf + (o ^ 16));
            bf16x8 bb = pack8(f0, f1);
            acc[0][ct] = __builtin_amdgcn_mfma_f32_16x16x32_bf16(a0, bb, acc[0][ct], 0, 0, 0);
            acc[1][ct] = __builtin_amdgcn_mfma_f32_16x16x32_bf16(a1, bb, acc[1][ct], 0, 0, 0);
        }
    };

    f32x4 acc_e[2][2], acc_i[2][2];
    #pragma unroll
    for (int i = 0; i < 2; ++i)
        #pragma unroll
        for (int j = 0; j < 2; ++j) {
            f32x4 z = {0.f, 0.f, 0.f, 0.f}; acc_e[i][j] = z; acc_i[i][j] = z;
        }

    FILL(0); FILL(1);
    #pragma unroll 1
    for (int c = 0; c < NC_TOT; ++c) {
        if (c + 1 < NC_TOT) asm volatile("s_waitcnt vmcnt(6)" ::: "memory");
        else                asm volatile("s_waitcnt vmcnt(0)" ::: "memory");
        __builtin_amdgcn_sched_barrier(0);
        __builtin_amdgcn_s_barrier();
        asm volatile("" ::: "memory");
        if (c < NC_E16) COMPUTE(lds + (c & 1) * CHUNKB, acc_e);
        else            COMPUTE(lds + (c & 1) * CHUNKB, acc_i);
        asm volatile("s_waitcnt lgkmcnt(0)" ::: "memory");
        __builtin_amdgcn_sched_barrier(0);
        __builtin_amdgcn_s_barrier();
        asm volatile("" ::: "memory");
        FILL(c + 2);
    }

    // cross-wave K-reduce via LDS (buffers dead now)
    float* red = (float*)lds;
    float* myE = red + (size_t)(w * 64 + lane) * 16;
    float* myI = red + 4096 + (size_t)(w * 64 + lane) * 16;
    #pragma unroll
    for (int i = 0; i < 2; ++i)
        #pragma unroll
        for (int j = 0; j < 2; ++j) {
            *(f32x4*)(myE + (i * 2 + j) * 4) = acc_e[i][j];
            *(f32x4*)(myI + (i * 2 + j) * 4) = acc_i[i][j];
        }
    __syncthreads();
    if (w < 2) {
        const float* base = red + (w ? 4096 : 0);
        float* dst = w ? syn_i : syn_e;
        float v[16];
        #pragma unroll
        for (int i = 0; i < 4; ++i) {
            float4 s0 = *(const float4*)(base + (size_t)(0 * 64 + lane) * 16 + i * 4);
            float4 s1 = *(const float4*)(base + (size_t)(1 * 64 + lane) * 16 + i * 4);
            float4 s2 = *(const float4*)(base + (size_t)(2 * 64 + lane) * 16 + i * 4);
            float4 s3 = *(const float4*)(base + (size_t)(3 * 64 + lane) * 16 + i * 4);
            v[i * 4 + 0] = s0.x + s1.x + s2.x + s3.x;
            v[i * 4 + 1] = s0.y + s1.y + s2.y + s3.y;
            v[i * 4 + 2] = s0.z + s1.z + s2.z + s3.z;
            v[i * 4 + 3] = s0.w + s1.w + s2.w + s3.w;
        }
        #pragma unroll
        for (int rt = 0; rt < 2; ++rt)
            #pragma unroll
            for (int ct = 0; ct < 2; ++ct)
                #pragma unroll
                for (int r = 0; r < 4; ++r) {
                    int s = rt * 16 + (lane >> 4) * 4 + r;   // C/D: col=lane&15, row=(lane>>4)*4+reg
                    if (s < SUB_NO)
                        dst[((size_t)b * SUB_NO + s) * T_DATA + t0 + ct * 16 + col] =
                            v[(rt * 2 + ct) * 4 + r];
                }
    }
}

// ---------------- K2: fused IIR conv (exact alpha-kernel recurrence) + tree --------
__global__ __launch_bounds__(256) void k_convtree(
    const float* __restrict__ syn_e, const float* __restrict__ syn_i,
    const float* __restrict__ W_syn, const float* __restrict__ Tau_syn,
    const float* __restrict__ Delta_syn, const float* __restrict__ W_sub,
    const float* __restrict__ V_o, const float* __restrict__ Theta,
    const float* __restrict__ C_den, float* __restrict__ out) {
    __shared__ float x_lds[2 * SUB_NO][XPAD];
    __shared__ float y2[2 * SUB_NO][CCHUNK + 1];
    __shared__ float cden[SUB_NO * SUB_NO];
    __shared__ float wexp[SUB_NO];
    __shared__ float th[SUB_NO];

    const int tid = threadIdx.x;
    const int b   = blockIdx.y;
    const int t0  = blockIdx.x * CCHUNK;

    for (int r = 0; r < 2 * SUB_NO; ++r) {
        int s = r >> 1, ch = r & 1;
        const float* src = (ch ? syn_i : syn_e) + (size_t)(b * SUB_NO + s) * T_DATA;
        for (int i = tid; i < XROW; i += 256) {
            int t = t0 - WARM + i;
            x_lds[r][i] = (t >= 0 && t < T_DATA) ? src[t] : 0.0f;
        }
    }
    for (int i = tid; i < SUB_NO * SUB_NO; i += 256) cden[i] = C_den[i];
    if (tid < SUB_NO) { wexp[tid] = expf(W_sub[tid]); th[tid] = Theta[tid]; }
    __syncthreads();

    if (tid < 2 * SUB_NO) {
        int s = tid >> 1, ch = tid & 1;
        float Tp = expf(Tau_syn[s * 2 + ch]);
        float dp = expf(Delta_syn[s * 2 + ch]);
        float rr = expf(-1.0f / Tp);
        float Bc = expf(W_syn[s * 2 + ch]) * expf(dp / Tp) / Tp;
        float s1 = 0.0f, s2 = 0.0f;
        for (int i = 0; i < WARM; ++i) {
            float u = s1 + x_lds[tid][i];
            s2 = rr * (s2 + u);
            s1 = rr * u;
        }
        for (int i = WARM; i < XROW; ++i) {
            y2[tid][i - WARM] = Bc * (s2 - dp * s1);   // k[0]=0: state uses x[<t] only
            float u = s1 + x_lds[tid][i];
            s2 = rr * (s2 + u);
            s1 = rr * u;
        }
    }
    __syncthreads();

    if (tid < CCHUNK) {
        int tt = t0 + tid;
        if (tt < T_DATA) {
            float xs[SUB_NO];
            #pragma unroll
            for (int s = SUB_NO - 1; s >= 0; --s) {
                float leaf = 0.0f;
                #pragma unroll
                for (int k = s + 1; k < SUB_NO; ++k)
                    leaf += cden[s * SUB_NO + k] * wexp[k] * xs[k];
                xs[s] = tanhf(y2[2 * s][tid] + y2[2 * s + 1][tid] + leaf + th[s]);
            }
            out[(size_t)b * T_DATA + tt] = xs[0] * wexp[0] + V_o[0];
        }
    }
}

extern "C" void kernel_launch(void* const* d_in, const int* in_sizes, int n_in,
                              void* d_out, int out_size, void* d_ws, size_t ws_size,
                              hipStream_t stream) {
    const float* S_e       = (const float*)d_in[0];
    const float* S_i       = (const float*)d_in[1];
    const float* C_den     = (const float*)d_in[2];
    const float* C_syn_e   = (const float*)d_in[3];
    const float* C_syn_i   = (const float*)d_in[4];
    const float* W_syn     = (const float*)d_in[5];
    const float* Tau_syn   = (const float*)d_in[6];
    const float* Delta_syn = (const float*)d_in[7];
    const float* W_sub     = (const float*)d_in[8];
    const float* V_o       = (const float*)d_in[9];
    const float* Theta     = (const float*)d_in[10];
    float* out = (float*)d_out;

    size_t syn_elems = (size_t)BATCH * SUB_NO * T_DATA;
    float* syn_e_ws = (float*)d_ws;
    float* syn_i_ws = syn_e_ws + syn_elems;
    ush*   Ae       = (ush*)(syn_i_ws + syn_elems);          // 128 KiB
    ush*   Ai       = Ae + (size_t)2 * NKS_E * 64 * 8;       // 32 KiB

    hipLaunchKernelGGL(k_build_afrag, dim3((2 * NKS_E * 64 + 2 * NKS_I * 64 + 255) / 256),
                       dim3(256), 0, stream, C_syn_e, C_syn_i, Ae, Ai);
    hipLaunchKernelGGL(k_proj, dim3(T_DATA / 32, BATCH), dim3(256), 0, stream,
                       S_e, S_i, Ae, Ai, syn_e_ws, syn_i_ws);
    hipLaunchKernelGGL(k_convtree, dim3((T_DATA + CCHUNK - 1) / CCHUNK, BATCH), dim3(256), 0, stream,
                       syn_e_ws, syn_i_ws, W_syn, Tau_syn, Delta_syn, W_sub, V_o, Theta, C_den, out);
}